// Round 1
// baseline (1694.558 us; speedup 1.0000x reference)
//
#include <hip/hip_runtime.h>
#include <math.h>

// ---------------------------------------------------------------------------
// R0 baseline: fp32 tiled vector GEMMs (no fp32 MFMA on CDNA4).
//   Stage 1: Q,K,V = X @ W^T          (gemm_nt, M=8192 N=1024 K=1024, x3)
//   Stage 2: S = (Q @ K^T) / 32       (gemm_nt batched, 2048x2048x1024 x4)
//   Stage 3: W = softmax_rows(S)      (in place in d_out weights region)
//   Stage 4: ctx = W @ V              (gemm_nn batched, 2048x1024x2048 x4)
// Tiles: 128x128x8, 256 threads, 8x8 microtile, LDS padded +4 (2-way max).
// Predicted: VALUBusy>70%, MfmaUtil=0, total ~1.5-3 ms.
// ---------------------------------------------------------------------------

constexpr int BM = 128, BN = 128, BK = 8;

// C = alpha * A * B^T
// A: M x K row-major, B: N x K row-major, C: M x N row-major. Batched via z.
__global__ __launch_bounds__(256)
void gemm_nt(const float* __restrict__ A, const float* __restrict__ B,
             float* __restrict__ C, int M, int N, int K,
             long sA, long sB, long sC, float alpha)
{
    __shared__ float As[BK][BM + 4];
    __shared__ float Bs[BK][BN + 4];

    const int bz = blockIdx.z;
    A += (long)bz * sA;
    B += (long)bz * sB;
    C += (long)bz * sC;

    const int tid  = threadIdx.x;
    const int tx   = tid & 15;       // 0..15
    const int ty   = tid >> 4;       // 0..15
    const int brow = blockIdx.y * BM;
    const int bcol = blockIdx.x * BN;

    const int lr = tid >> 1;         // 0..127 (staging row)
    const int lc = (tid & 1) * 4;    // 0 or 4 (staging col group)

    float acc[8][8];
    #pragma unroll
    for (int i = 0; i < 8; ++i)
        #pragma unroll
        for (int j = 0; j < 8; ++j) acc[i][j] = 0.f;

    for (int kt = 0; kt < K; kt += BK) {
        float4 av = *reinterpret_cast<const float4*>(&A[(long)(brow + lr) * K + kt + lc]);
        float4 bv = *reinterpret_cast<const float4*>(&B[(long)(bcol + lr) * K + kt + lc]);
        __syncthreads();
        As[lc + 0][lr] = av.x; As[lc + 1][lr] = av.y;
        As[lc + 2][lr] = av.z; As[lc + 3][lr] = av.w;
        Bs[lc + 0][lr] = bv.x; Bs[lc + 1][lr] = bv.y;
        Bs[lc + 2][lr] = bv.z; Bs[lc + 3][lr] = bv.w;
        __syncthreads();

        #pragma unroll
        for (int k = 0; k < BK; ++k) {
            float4 a0 = *reinterpret_cast<const float4*>(&As[k][ty * 8]);
            float4 a1 = *reinterpret_cast<const float4*>(&As[k][ty * 8 + 4]);
            float4 b0 = *reinterpret_cast<const float4*>(&Bs[k][tx * 8]);
            float4 b1 = *reinterpret_cast<const float4*>(&Bs[k][tx * 8 + 4]);
            float a[8]  = {a0.x, a0.y, a0.z, a0.w, a1.x, a1.y, a1.z, a1.w};
            float bb[8] = {b0.x, b0.y, b0.z, b0.w, b1.x, b1.y, b1.z, b1.w};
            #pragma unroll
            for (int i = 0; i < 8; ++i)
                #pragma unroll
                for (int j = 0; j < 8; ++j)
                    acc[i][j] = fmaf(a[i], bb[j], acc[i][j]);
        }
    }

    #pragma unroll
    for (int i = 0; i < 8; ++i) {
        float4 c0 = {acc[i][0] * alpha, acc[i][1] * alpha, acc[i][2] * alpha, acc[i][3] * alpha};
        float4 c1 = {acc[i][4] * alpha, acc[i][5] * alpha, acc[i][6] * alpha, acc[i][7] * alpha};
        float* crow = &C[(long)(brow + ty * 8 + i) * N + bcol + tx * 8];
        *reinterpret_cast<float4*>(crow)     = c0;
        *reinterpret_cast<float4*>(crow + 4) = c1;
    }
}

// C = A * B
// A: M x K row-major, B: K x N row-major, C: M x N row-major. Batched via z.
__global__ __launch_bounds__(256)
void gemm_nn(const float* __restrict__ A, const float* __restrict__ B,
             float* __restrict__ C, int M, int N, int K,
             long sA, long sB, long sC)
{
    __shared__ float As[BK][BM + 4];
    __shared__ float Bs[BK][BN + 4];

    const int bz = blockIdx.z;
    A += (long)bz * sA;
    B += (long)bz * sB;
    C += (long)bz * sC;

    const int tid  = threadIdx.x;
    const int tx   = tid & 15;
    const int ty   = tid >> 4;
    const int brow = blockIdx.y * BM;
    const int bcol = blockIdx.x * BN;

    const int lr = tid >> 1;         // A staging row 0..127
    const int lc = (tid & 1) * 4;    // A staging col group

    const int br = tid >> 5;         // B staging row 0..7
    const int bc = (tid & 31) * 4;   // B staging col 0..124

    float acc[8][8];
    #pragma unroll
    for (int i = 0; i < 8; ++i)
        #pragma unroll
        for (int j = 0; j < 8; ++j) acc[i][j] = 0.f;

    for (int kt = 0; kt < K; kt += BK) {
        float4 av = *reinterpret_cast<const float4*>(&A[(long)(brow + lr) * K + kt + lc]);
        float4 bv = *reinterpret_cast<const float4*>(&B[(long)(kt + br) * N + bcol + bc]);
        __syncthreads();
        As[lc + 0][lr] = av.x; As[lc + 1][lr] = av.y;
        As[lc + 2][lr] = av.z; As[lc + 3][lr] = av.w;
        *reinterpret_cast<float4*>(&Bs[br][bc]) = bv;
        __syncthreads();

        #pragma unroll
        for (int k = 0; k < BK; ++k) {
            float4 a0 = *reinterpret_cast<const float4*>(&As[k][ty * 8]);
            float4 a1 = *reinterpret_cast<const float4*>(&As[k][ty * 8 + 4]);
            float4 b0 = *reinterpret_cast<const float4*>(&Bs[k][tx * 8]);
            float4 b1 = *reinterpret_cast<const float4*>(&Bs[k][tx * 8 + 4]);
            float a[8]  = {a0.x, a0.y, a0.z, a0.w, a1.x, a1.y, a1.z, a1.w};
            float bb[8] = {b0.x, b0.y, b0.z, b0.w, b1.x, b1.y, b1.z, b1.w};
            #pragma unroll
            for (int i = 0; i < 8; ++i)
                #pragma unroll
                for (int j = 0; j < 8; ++j)
                    acc[i][j] = fmaf(a[i], bb[j], acc[i][j]);
        }
    }

    #pragma unroll
    for (int i = 0; i < 8; ++i) {
        float4 c0 = {acc[i][0], acc[i][1], acc[i][2], acc[i][3]};
        float4 c1 = {acc[i][4], acc[i][5], acc[i][6], acc[i][7]};
        float* crow = &C[(long)(brow + ty * 8 + i) * N + bcol + tx * 8];
        *reinterpret_cast<float4*>(crow)     = c0;
        *reinterpret_cast<float4*>(crow + 4) = c1;
    }
}

// In-place row softmax; one block per row of 2048 floats.
__global__ __launch_bounds__(256)
void softmax_rows(float* __restrict__ W)
{
    float* p = W + (long)blockIdx.x * 2048;
    const int tid  = threadIdx.x;
    const int wid  = tid >> 6;
    const int lane = tid & 63;

    float4 v0 = reinterpret_cast<const float4*>(p)[tid];
    float4 v1 = reinterpret_cast<const float4*>(p)[tid + 256];

    float m = fmaxf(fmaxf(fmaxf(v0.x, v0.y), fmaxf(v0.z, v0.w)),
                    fmaxf(fmaxf(v1.x, v1.y), fmaxf(v1.z, v1.w)));
    #pragma unroll
    for (int off = 32; off >= 1; off >>= 1)
        m = fmaxf(m, __shfl_xor(m, off));

    __shared__ float red[8];
    if (lane == 0) red[wid] = m;
    __syncthreads();
    m = fmaxf(fmaxf(red[0], red[1]), fmaxf(red[2], red[3]));

    v0.x = expf(v0.x - m); v0.y = expf(v0.y - m);
    v0.z = expf(v0.z - m); v0.w = expf(v0.w - m);
    v1.x = expf(v1.x - m); v1.y = expf(v1.y - m);
    v1.z = expf(v1.z - m); v1.w = expf(v1.w - m);

    float s = (v0.x + v0.y + v0.z + v0.w) + (v1.x + v1.y + v1.z + v1.w);
    #pragma unroll
    for (int off = 32; off >= 1; off >>= 1)
        s += __shfl_xor(s, off);
    __syncthreads();              // red[0..3] reads done
    if (lane == 0) red[4 + wid] = s;
    __syncthreads();
    s = (red[4] + red[5]) + (red[6] + red[7]);

    const float inv = 1.f / s;
    v0.x *= inv; v0.y *= inv; v0.z *= inv; v0.w *= inv;
    v1.x *= inv; v1.y *= inv; v1.z *= inv; v1.w *= inv;
    reinterpret_cast<float4*>(p)[tid]       = v0;
    reinterpret_cast<float4*>(p)[tid + 256] = v1;
}

extern "C" void kernel_launch(void* const* d_in, const int* in_sizes, int n_in,
                              void* d_out, int out_size, void* d_ws, size_t ws_size,
                              hipStream_t stream)
{
    const float* X  = (const float*)d_in[0];   // [4,2048,1024]
    const float* Wq = (const float*)d_in[1];   // [1024,1024] (out,in)
    const float* Wk = (const float*)d_in[2];
    const float* Wv = (const float*)d_in[3];

    const long BT = 4L * 2048;                 // 8192 rows total
    const long D  = 1024;
    const long S  = 2048;                      // seq len per batch

    float* ctx = (float*)d_out;                // [4,2048,1024]
    float* wts = (float*)d_out + BT * D;       // [4,2048,2048]

    float* Q = (float*)d_ws;                   // 3 x 8192x1024 fp32 = 96 MB
    float* K = Q + BT * D;
    float* V = K + BT * D;

    dim3 blk(256);

    // Stage 1: projections  Q/K/V[m,k] = sum_d X[m,d] * W[k,d]
    dim3 gproj(D / BN, BT / BM, 1);            // (8, 64)
    gemm_nt<<<gproj, blk, 0, stream>>>(X, Wq, Q, BT, D, D, 0, 0, 0, 1.f);
    gemm_nt<<<gproj, blk, 0, stream>>>(X, Wk, K, BT, D, D, 0, 0, 0, 1.f);
    gemm_nt<<<gproj, blk, 0, stream>>>(X, Wv, V, BT, D, D, 0, 0, 0, 1.f);

    // Stage 2: scores S_b = Q_b K_b^T / 32  -> weights region of d_out
    dim3 gsc(S / BN, S / BM, 4);               // (16, 16, 4)
    gemm_nt<<<gsc, blk, 0, stream>>>(Q, K, wts, S, S, D,
                                     S * D, S * D, S * S, 0.03125f);

    // Stage 3: softmax rows in place
    softmax_rows<<<dim3(BT), blk, 0, stream>>>(wts);

    // Stage 4: context_b = W_b V_b
    dim3 gctx(D / BN, S / BM, 4);              // (8, 16, 4)
    gemm_nn<<<gctx, blk, 0, stream>>>(wts, V, ctx, S, D, S,
                                      S * S, S * D, S * D);
}

// Round 3
// 378.009 us; speedup vs baseline: 4.4828x; 4.4828x over previous
//
#include <hip/hip_runtime.h>
#include <math.h>

// ---------------------------------------------------------------------------
// R2 = R1 resubmit (R1 hit GPUAcquisitionTimeout; never compiled/ran).
// bf16 MFMA everywhere (m97 structure: 128x128 tile, BK=32,
//     global_load_lds width=16, 4 waves x (4x4) 16x16x32 fragments).
// All GEMMs in NT form:
//   Xb,Wqb,Wkb,Wvb = cast_bf16(X, Wq, Wk, Wv)
//   Qb  = NT(Xb , Wqb)            [8192,1024] bf16
//   Kb  = NT(Xb , Wkb)            [8192,1024] bf16
//   Vtb = NT(Wvb, Xb )            [1024,8192] bf16   (V stored transposed)
//   S_b = NT(Qb_b, Kb_b) / 32     [2048,2048] f32 -> d_out weights region
//   softmax rows in place (f32) + bf16 copy Wbf
//   ctx_b = NT(Wbf_b, Vtb_b)      [2048,1024] f32 -> d_out context region
// ws layout (MiB): Xb[0,16) Wqb[16,18) Wkb[18,20) Wvb[20,22) Qb[22,38)
//   Kb[38,54) Vtb[54,70); Wbf reuses [0,32) (Xb/W*/Qb dead by softmax time).
// Predicted: total ~250-350us; GEMMs MfmaUtil 30-40%; softmax top BW kernel.
// ---------------------------------------------------------------------------

typedef __bf16 bf16;
typedef __bf16 bf16x4 __attribute__((ext_vector_type(4)));
typedef __bf16 bf16x8 __attribute__((ext_vector_type(8)));
typedef float  f32x4  __attribute__((ext_vector_type(4)));

#define GLD_TO_LDS(g, l) __builtin_amdgcn_global_load_lds(                    \
    (const __attribute__((address_space(1))) void*)(g),                       \
    (__attribute__((address_space(3))) void*)(l), 16, 0, 0)

// C[M,N] = alpha * A[M,K] * B[N,K]^T ; row-major; bf16 in, f32 accumulate.
// OUT: 0 = f32 store, 1 = bf16 store. Batched via blockIdx.z with elem strides.
template<int OUT>
__global__ __launch_bounds__(256)
void gemm_bt(const bf16* __restrict__ A, const bf16* __restrict__ B,
             void* __restrict__ Cp, int K, int lda, int ldb, int ldc,
             long sA, long sB, long sC, float alpha)
{
    __shared__ __align__(16) bf16 As[128][32];
    __shared__ __align__(16) bf16 Bs[128][32];

    const int bz = blockIdx.z;
    A += bz * sA;
    B += bz * sB;

    const int t    = threadIdx.x;
    const int brow = blockIdx.y * 128;
    const int bcol = blockIdx.x * 128;

    const int wid  = t >> 6;
    const int lane = t & 63;
    const int wm   = (wid >> 1) * 64;   // wave row offset in tile
    const int wn   = (wid & 1) * 64;    // wave col offset in tile
    const int fr   = lane & 15;         // fragment row (A) / col (B)
    const int fk   = (lane >> 4) * 8;   // fragment k offset
    const int fq   = (lane >> 4) * 4;   // C/D row group

    // staging: thread t covers LDS bytes [t*16, t*16+16) = row (t>>2), k (t&3)*8
    const int  srow = t >> 2;
    const int  scol = (t & 3) * 8;
    const long a0   = (long)(brow + srow) * lda + scol;
    const long b0   = (long)(bcol + srow) * ldb + scol;
    char* al = (char*)&As[0][0] + t * 16;
    char* bl = (char*)&Bs[0][0] + t * 16;

    f32x4 acc[4][4] = {};

    for (int kt = 0; kt < K; kt += 32) {
        GLD_TO_LDS(A + a0 + kt,            al);
        GLD_TO_LDS(A + a0 + kt + 64 * lda, al + 4096);
        GLD_TO_LDS(B + b0 + kt,            bl);
        GLD_TO_LDS(B + b0 + kt + 64 * ldb, bl + 4096);
        __syncthreads();   // drains vmcnt(0): LDS tile ready for all waves

        bf16x8 af[4], bfr[4];
        #pragma unroll
        for (int i = 0; i < 4; ++i)
            af[i] = *reinterpret_cast<const bf16x8*>(&As[wm + i * 16 + fr][fk]);
        #pragma unroll
        for (int j = 0; j < 4; ++j)
            bfr[j] = *reinterpret_cast<const bf16x8*>(&Bs[wn + j * 16 + fr][fk]);

        #pragma unroll
        for (int i = 0; i < 4; ++i)
            #pragma unroll
            for (int j = 0; j < 4; ++j)
                acc[i][j] = __builtin_amdgcn_mfma_f32_16x16x32_bf16(
                                af[i], bfr[j], acc[i][j], 0, 0, 0);
        __syncthreads();   // all waves done reading before next overwrite
    }

    // C/D layout (m89-verified): col = lane&15, row = (lane>>4)*4 + reg
    #pragma unroll
    for (int i = 0; i < 4; ++i) {
        #pragma unroll
        for (int j = 0; j < 4; ++j) {
            const int ccol = bcol + wn + j * 16 + fr;
            #pragma unroll
            for (int r = 0; r < 4; ++r) {
                const long crow = brow + wm + i * 16 + fq + r;
                const float v = acc[i][j][r] * alpha;
                if constexpr (OUT == 0) {
                    ((float*)Cp + bz * sC)[crow * ldc + ccol] = v;
                } else {
                    ((bf16*)Cp + bz * sC)[crow * ldc + ccol] = (bf16)v;
                }
            }
        }
    }
}

// fp32 -> bf16 cast, vectorized x4, grid-stride.
__global__ __launch_bounds__(256)
void cast_bf16(const float* __restrict__ in, bf16* __restrict__ out, int n4)
{
    int i = blockIdx.x * 256 + threadIdx.x;
    const int stride = gridDim.x * 256;
    for (; i < n4; i += stride) {
        float4 v = reinterpret_cast<const float4*>(in)[i];
        bf16x4 o = { (bf16)v.x, (bf16)v.y, (bf16)v.z, (bf16)v.w };
        reinterpret_cast<bf16x4*>(out)[i] = o;
    }
}

// In-place row softmax (f32) + bf16 copy; one block per row of 2048.
__global__ __launch_bounds__(256)
void softmax_rows(float* __restrict__ W, bf16* __restrict__ Wb)
{
    float* p  = W  + (long)blockIdx.x * 2048;
    bf16*  pb = Wb + (long)blockIdx.x * 2048;
    const int tid  = threadIdx.x;
    const int wid  = tid >> 6;
    const int lane = tid & 63;

    float4 v0 = reinterpret_cast<const float4*>(p)[tid];
    float4 v1 = reinterpret_cast<const float4*>(p)[tid + 256];

    float m = fmaxf(fmaxf(fmaxf(v0.x, v0.y), fmaxf(v0.z, v0.w)),
                    fmaxf(fmaxf(v1.x, v1.y), fmaxf(v1.z, v1.w)));
    #pragma unroll
    for (int off = 32; off >= 1; off >>= 1)
        m = fmaxf(m, __shfl_xor(m, off));

    __shared__ float red[8];
    if (lane == 0) red[wid] = m;
    __syncthreads();
    m = fmaxf(fmaxf(red[0], red[1]), fmaxf(red[2], red[3]));

    v0.x = expf(v0.x - m); v0.y = expf(v0.y - m);
    v0.z = expf(v0.z - m); v0.w = expf(v0.w - m);
    v1.x = expf(v1.x - m); v1.y = expf(v1.y - m);
    v1.z = expf(v1.z - m); v1.w = expf(v1.w - m);

    float s = (v0.x + v0.y + v0.z + v0.w) + (v1.x + v1.y + v1.z + v1.w);
    #pragma unroll
    for (int off = 32; off >= 1; off >>= 1)
        s += __shfl_xor(s, off);
    __syncthreads();
    if (lane == 0) red[4 + wid] = s;
    __syncthreads();
    s = (red[4] + red[5]) + (red[6] + red[7]);

    const float inv = 1.f / s;
    v0.x *= inv; v0.y *= inv; v0.z *= inv; v0.w *= inv;
    v1.x *= inv; v1.y *= inv; v1.z *= inv; v1.w *= inv;
    reinterpret_cast<float4*>(p)[tid]       = v0;
    reinterpret_cast<float4*>(p)[tid + 256] = v1;
    bf16x4 b0 = { (bf16)v0.x, (bf16)v0.y, (bf16)v0.z, (bf16)v0.w };
    bf16x4 b1 = { (bf16)v1.x, (bf16)v1.y, (bf16)v1.z, (bf16)v1.w };
    reinterpret_cast<bf16x4*>(pb)[tid]       = b0;
    reinterpret_cast<bf16x4*>(pb)[tid + 256] = b1;
}

extern "C" void kernel_launch(void* const* d_in, const int* in_sizes, int n_in,
                              void* d_out, int out_size, void* d_ws, size_t ws_size,
                              hipStream_t stream)
{
    const float* X  = (const float*)d_in[0];   // [4,2048,1024]
    const float* Wq = (const float*)d_in[1];   // [1024,1024]
    const float* Wk = (const float*)d_in[2];
    const float* Wv = (const float*)d_in[3];

    const long BT = 4L * 2048;                 // 8192 total rows
    const long D  = 1024;
    const long S  = 2048;
    const long MiB = 1024 * 1024;

    float* ctx = (float*)d_out;                // [4,2048,1024]
    float* wts = (float*)d_out + BT * D;       // [4,2048,2048]

    char* ws  = (char*)d_ws;
    bf16* Xb  = (bf16*)(ws);                   // 16 MiB
    bf16* Wqb = (bf16*)(ws + 16 * MiB);        //  2 MiB
    bf16* Wkb = (bf16*)(ws + 18 * MiB);
    bf16* Wvb = (bf16*)(ws + 20 * MiB);
    bf16* Qb  = (bf16*)(ws + 22 * MiB);        // 16 MiB
    bf16* Kb  = (bf16*)(ws + 38 * MiB);        // 16 MiB
    bf16* Vtb = (bf16*)(ws + 54 * MiB);        // 16 MiB [1024][8192]
    bf16* Wbf = (bf16*)(ws);                   // 32 MiB, reuses dead region

    dim3 blk(256);

    // casts
    cast_bf16<<<dim3(2048), blk, 0, stream>>>(X,  Xb,  (int)(BT * D / 4));
    cast_bf16<<<dim3(512),  blk, 0, stream>>>(Wq, Wqb, (int)(D * D / 4));
    cast_bf16<<<dim3(512),  blk, 0, stream>>>(Wk, Wkb, (int)(D * D / 4));
    cast_bf16<<<dim3(512),  blk, 0, stream>>>(Wv, Wvb, (int)(D * D / 4));

    // projections: Q/K [8192,1024] = NT(Xb, W*) ; Vt [1024,8192] = NT(Wvb, Xb)
    gemm_bt<1><<<dim3(8, 64, 1), blk, 0, stream>>>(Xb, Wqb, Qb, 1024,
                                                   1024, 1024, 1024, 0, 0, 0, 1.f);
    gemm_bt<1><<<dim3(8, 64, 1), blk, 0, stream>>>(Xb, Wkb, Kb, 1024,
                                                   1024, 1024, 1024, 0, 0, 0, 1.f);
    gemm_bt<1><<<dim3(64, 8, 1), blk, 0, stream>>>(Wvb, Xb, Vtb, 1024,
                                                   1024, 1024, 8192, 0, 0, 0, 1.f);

    // scores: S_b = NT(Qb_b, Kb_b) / 32 -> f32 weights region
    gemm_bt<0><<<dim3(16, 16, 4), blk, 0, stream>>>(Qb, Kb, wts, 1024,
                                                    1024, 1024, 2048,
                                                    S * D, S * D, S * S, 0.03125f);

    // softmax rows (f32 in place) + bf16 copy
    softmax_rows<<<dim3(BT), blk, 0, stream>>>(wts, Wbf);

    // context: ctx_b = NT(Wbf_b, Vtb_b) ; Vt batch b = columns [b*2048, ...)
    gemm_bt<0><<<dim3(8, 16, 4), blk, 0, stream>>>(Wbf, Vtb, ctx, 2048,
                                                   2048, 8192, 1024,
                                                   S * S, S, S * D, 1.f);
}

// Round 5
// 309.613 us; speedup vs baseline: 5.4732x; 1.2209x over previous
//
#include <hip/hip_runtime.h>
#include <math.h>

// ---------------------------------------------------------------------------
// R4 = R3 resubmit (R3 hit GPUAcquisitionTimeout; never compiled/ran).
// 256x256 8-phase deep-pipelined bf16 MFMA GEMM (T2+T3+T4+T5), plain HIP.
//   BK=64, 8 waves (2M x 4N), per-wave 128x64 output, acc[8][4] f32x4.
//   LDS 128 KiB: A[2][256][64] + B[2][256][64] bf16, XOR-swizzle slot^=(row&7)
//   (write side: linear LDS dest + inverse-swizzled GLOBAL source; read side:
//    same XOR -> bank-optimal ds_read_b128, zero excess conflict by derivation)
//   Schedule/iter (tiles cur,cur+1): ph0:A0(cur+1) ph1:A1(cur+1) ph2:B0(cur+2)
//   ph3:B1(cur+2)+vmcnt(4) ph4:A0(cur+2) ph5:A1(cur+2) ph6:B0(cur+3)
//   ph7:B1(cur+3)+vmcnt(4).  Slot-death safety: B(t) last read ph0, A(t) ph3,
//   B(t+1) ph4, A(t+1) ph7 -> every stage is >=1 phase after its slot dies.
//   vmcnt(4): everything older than newest 4 loads has landed -> tile cur+1
//   complete before ph4 reads, tile cur+2 complete before next iter's ph0.
//   Tail: clamp source tile (uniform counts; clamped data lands in dead slot).
// Pipeline: casts -> QK-proj (fused [2048,1024] W) -> Vt-proj -> scores ->
//           softmax(+bf16 copy) -> PV.
// Predicted: MfmaUtil 50-62%, bank-conflicts ~0, total ~180-220us.
// ---------------------------------------------------------------------------

typedef __bf16 bf16;
typedef __bf16 bf16x4 __attribute__((ext_vector_type(4)));
typedef __bf16 bf16x8 __attribute__((ext_vector_type(8)));
typedef float  f32x4  __attribute__((ext_vector_type(4)));

#define GLD_TO_LDS(g, l) __builtin_amdgcn_global_load_lds(                    \
    (const __attribute__((address_space(1))) void*)(g),                       \
    (__attribute__((address_space(3))) void*)(l), 16, 0, 0)

// stage one 128-row half-tile (2 x global_load_lds, 8KB each):
// linear LDS dest (thread t -> byte t*16), source col pre-XOR'd in Row ptrs.
#define STAGE_A(tc, P, h) do {                                                \
    const bf16* _s = aRow + (long)((h) * 128) * lda + (long)(tc) * 64;        \
    char* _d = ldsA + (P) * 32768 + (h) * 16384 + t * 16;                     \
    GLD_TO_LDS(_s, _d); GLD_TO_LDS(_s + 64L * lda, _d + 8192); } while (0)
#define STAGE_B(tc, P, h) do {                                                \
    const bf16* _s = bRow + (long)((h) * 128) * ldb + (long)(tc) * 64;        \
    char* _d = ldsB + (P) * 32768 + (h) * 16384 + t * 16;                     \
    GLD_TO_LDS(_s, _d); GLD_TO_LDS(_s + 64L * ldb, _d + 8192); } while (0)
#define VMCNT4 asm volatile("s_waitcnt vmcnt(4)" ::: "memory")

// C[M,N] = alpha * A[M,K] * B[N,K]^T ; bf16 in, f32 acc. OUT: 0=f32, 1=bf16.
// Requires M%256==0, N%256==0, K%128==0 (nkt = K/64 even, >=2). Batch via z.
template<int OUT>
__global__ __launch_bounds__(512, 2)
void gemm8(const bf16* __restrict__ A, const bf16* __restrict__ B,
           void* __restrict__ Cp, int nkt, int lda, int ldb, int ldc,
           long sA, long sB, long sC, float alpha)
{
    __shared__ __align__(16) char smem[131072];
    char* ldsA = smem;            // [2][256][64] bf16 (swizzled slots)
    char* ldsB = smem + 65536;

    const int bz = blockIdx.z;
    A += bz * sA;
    B += bz * sB;

    const int t    = threadIdx.x;
    const int wid  = t >> 6;
    const int lane = t & 63;
    const int wr   = wid >> 2;          // 0..1 : wave M-block (128 rows)
    const int wn   = wid & 3;           // 0..3 : wave N-block (64 cols)
    const int fr   = lane & 15;         // frag row (A) / col-row (B)
    const int g    = lane >> 4;         // 0..3
    const int brow = blockIdx.y * 256;
    const int bcol = blockIdx.x * 256;

    // staging source (pre-swizzled global col so linear LDS holds swz layout)
    const int  srow = t >> 3;                              // 0..63
    const int  scol = ((t & 7) ^ ((t >> 3) & 7)) * 8;      // elements
    const bf16* aRow = A + (long)(brow + srow) * lda + scol;
    const bf16* bRow = B + (long)(bcol + srow) * ldb + scol;

    // ds_read bases; col = (ks*64 + g*16) ^ ((fr&7)<<4)
    const int  c0  = (g * 16) ^ ((fr & 7) << 4);
    const int  c1  = c0 ^ 64;
    const char* aRd = ldsA + (wr * 128 + fr) * 128;
    const char* bRd = ldsB + (wn * 64 + fr) * 128;

    f32x4 acc[8][4] = {};
    bf16x8 bfrag[4][2];

    // prologue: stage tiles 0,1 fully (16 loads), drain tile 0
    STAGE_A(0, 0, 0); STAGE_A(0, 0, 1); STAGE_B(0, 0, 0); STAGE_B(0, 0, 1);
    STAGE_A(1, 1, 0); STAGE_A(1, 1, 1); STAGE_B(1, 1, 0); STAGE_B(1, 1, 1);
    asm volatile("s_waitcnt vmcnt(8)" ::: "memory");
    __builtin_amdgcn_s_barrier();

    const int niter = nkt >> 1;
    for (int it = 0; it < niter; ++it) {
        const int cur = 2 * it;
        const int tc2 = (cur + 2 < nkt) ? cur + 2 : nkt - 1;
        const int tc3 = (cur + 3 < nkt) ? cur + 3 : nkt - 1;
        #pragma unroll
        for (int ph = 0; ph < 8; ++ph) {
            const int q = ph & 3;       // quadrant (2 M-frags)
            const int P = ph >> 2;      // tile parity / LDS slot

            if (q == 0) {               // B-frags once per K-tile (8 reads)
                #pragma unroll
                for (int n = 0; n < 4; ++n) {
                    bfrag[n][0] = *reinterpret_cast<const bf16x8*>(
                        bRd + P * 32768 + n * 2048 + c0);
                    bfrag[n][1] = *reinterpret_cast<const bf16x8*>(
                        bRd + P * 32768 + n * 2048 + c1);
                }
            }
            bf16x8 af[2][2];            // A-frags for this quadrant (4 reads)
            #pragma unroll
            for (int i = 0; i < 2; ++i) {
                af[i][0] = *reinterpret_cast<const bf16x8*>(
                    aRd + P * 32768 + (2 * q + i) * 2048 + c0);
                af[i][1] = *reinterpret_cast<const bf16x8*>(
                    aRd + P * 32768 + (2 * q + i) * 2048 + c1);
            }

            // staging schedule (slot-death-safe, uniform counts)
            if (ph == 0) STAGE_A(cur + 1, 1, 0);
            if (ph == 1) STAGE_A(cur + 1, 1, 1);
            if (ph == 2) STAGE_B(tc2, 0, 0);
            if (ph == 3) { STAGE_B(tc2, 0, 1); VMCNT4; }
            if (ph == 4) STAGE_A(tc2, 0, 0);
            if (ph == 5) STAGE_A(tc2, 0, 1);
            if (ph == 6) STAGE_B(tc3, 1, 0);
            if (ph == 7) { STAGE_B(tc3, 1, 1); VMCNT4; }

            __builtin_amdgcn_s_barrier();
            __builtin_amdgcn_s_setprio(1);
            #pragma unroll
            for (int i = 0; i < 2; ++i)
                #pragma unroll
                for (int n = 0; n < 4; ++n) {
                    acc[2 * q + i][n] = __builtin_amdgcn_mfma_f32_16x16x32_bf16(
                        af[i][0], bfrag[n][0], acc[2 * q + i][n], 0, 0, 0);
                    acc[2 * q + i][n] = __builtin_amdgcn_mfma_f32_16x16x32_bf16(
                        af[i][1], bfrag[n][1], acc[2 * q + i][n], 0, 0, 0);
                }
            __builtin_amdgcn_s_setprio(0);
            __builtin_amdgcn_s_barrier();
        }
    }

    // epilogue: C/D layout col = lane&15, row = (lane>>4)*4 + rr (m89-verified)
    #pragma unroll
    for (int m = 0; m < 8; ++m) {
        #pragma unroll
        for (int n = 0; n < 4; ++n) {
            const int ccol = bcol + wn * 64 + n * 16 + fr;
            #pragma unroll
            for (int rr = 0; rr < 4; ++rr) {
                const long crow = brow + wr * 128 + m * 16 + g * 4 + rr;
                const float v = acc[m][n][rr] * alpha;
                if constexpr (OUT == 0) {
                    ((float*)Cp + bz * sC)[crow * ldc + ccol] = v;
                } else {
                    ((bf16*)Cp + bz * sC)[crow * ldc + ccol] = (bf16)v;
                }
            }
        }
    }
}

// fp32 -> bf16 cast, vectorized x4, grid-stride.
__global__ __launch_bounds__(256)
void cast_bf16(const float* __restrict__ in, bf16* __restrict__ out, int n4)
{
    int i = blockIdx.x * 256 + threadIdx.x;
    const int stride = gridDim.x * 256;
    for (; i < n4; i += stride) {
        float4 v = reinterpret_cast<const float4*>(in)[i];
        bf16x4 o = { (bf16)v.x, (bf16)v.y, (bf16)v.z, (bf16)v.w };
        reinterpret_cast<bf16x4*>(out)[i] = o;
    }
}

// In-place row softmax (f32) + bf16 copy; one block per row of 2048.
__global__ __launch_bounds__(256)
void softmax_rows(float* __restrict__ W, bf16* __restrict__ Wb)
{
    float* p  = W  + (long)blockIdx.x * 2048;
    bf16*  pb = Wb + (long)blockIdx.x * 2048;
    const int tid  = threadIdx.x;
    const int wid  = tid >> 6;
    const int lane = tid & 63;

    float4 v0 = reinterpret_cast<const float4*>(p)[tid];
    float4 v1 = reinterpret_cast<const float4*>(p)[tid + 256];

    float m = fmaxf(fmaxf(fmaxf(v0.x, v0.y), fmaxf(v0.z, v0.w)),
                    fmaxf(fmaxf(v1.x, v1.y), fmaxf(v1.z, v1.w)));
    #pragma unroll
    for (int off = 32; off >= 1; off >>= 1)
        m = fmaxf(m, __shfl_xor(m, off));

    __shared__ float red[8];
    if (lane == 0) red[wid] = m;
    __syncthreads();
    m = fmaxf(fmaxf(red[0], red[1]), fmaxf(red[2], red[3]));

    v0.x = expf(v0.x - m); v0.y = expf(v0.y - m);
    v0.z = expf(v0.z - m); v0.w = expf(v0.w - m);
    v1.x = expf(v1.x - m); v1.y = expf(v1.y - m);
    v1.z = expf(v1.z - m); v1.w = expf(v1.w - m);

    float s = (v0.x + v0.y + v0.z + v0.w) + (v1.x + v1.y + v1.z + v1.w);
    #pragma unroll
    for (int off = 32; off >= 1; off >>= 1)
        s += __shfl_xor(s, off);
    __syncthreads();
    if (lane == 0) red[4 + wid] = s;
    __syncthreads();
    s = (red[4] + red[5]) + (red[6] + red[7]);

    const float inv = 1.f / s;
    v0.x *= inv; v0.y *= inv; v0.z *= inv; v0.w *= inv;
    v1.x *= inv; v1.y *= inv; v1.z *= inv; v1.w *= inv;
    reinterpret_cast<float4*>(p)[tid]       = v0;
    reinterpret_cast<float4*>(p)[tid + 256] = v1;
    bf16x4 b0 = { (bf16)v0.x, (bf16)v0.y, (bf16)v0.z, (bf16)v0.w };
    bf16x4 b1 = { (bf16)v1.x, (bf16)v1.y, (bf16)v1.z, (bf16)v1.w };
    reinterpret_cast<bf16x4*>(pb)[tid]       = b0;
    reinterpret_cast<bf16x4*>(pb)[tid + 256] = b1;
}

extern "C" void kernel_launch(void* const* d_in, const int* in_sizes, int n_in,
                              void* d_out, int out_size, void* d_ws, size_t ws_size,
                              hipStream_t stream)
{
    const float* X  = (const float*)d_in[0];   // [4,2048,1024]
    const float* Wq = (const float*)d_in[1];   // [1024,1024]
    const float* Wk = (const float*)d_in[2];
    const float* Wv = (const float*)d_in[3];

    const long BT = 4L * 2048;                 // 8192 total rows
    const long D  = 1024;
    const long S  = 2048;
    const long MiB = 1024 * 1024;

    float* ctx = (float*)d_out;                // [4,2048,1024]
    float* wts = (float*)d_out + BT * D;       // [4,2048,2048]

    char* ws   = (char*)d_ws;
    bf16* Xb   = (bf16*)(ws);                  // 16 MiB [0,16)
    bf16* Wqkb = (bf16*)(ws + 16 * MiB);       //  4 MiB [16,20)  [2048,1024]
    bf16* Wvb  = (bf16*)(ws + 20 * MiB);       //  2 MiB [20,22)
    bf16* QKb  = (bf16*)(ws + 22 * MiB);       // 32 MiB [22,54)  [8192,2048]
    bf16* Vtb  = (bf16*)(ws + 54 * MiB);       // 16 MiB [54,70)  [1024,8192]
    bf16* Wbf  = (bf16*)(ws);                  // 32 MiB, aliases dead [0,32)

    dim3 blk(256), blk8(512);

    // casts (Wq/Wk concatenated into one [2048,1024] operand)
    cast_bf16<<<dim3(2048), blk, 0, stream>>>(X,  Xb,   (int)(BT * D / 4));
    cast_bf16<<<dim3(512),  blk, 0, stream>>>(Wq, Wqkb, (int)(D * D / 4));
    cast_bf16<<<dim3(512),  blk, 0, stream>>>(Wk, Wqkb + D * D, (int)(D * D / 4));
    cast_bf16<<<dim3(512),  blk, 0, stream>>>(Wv, Wvb,  (int)(D * D / 4));

    // fused QK projection: QKb[8192,2048] = NT(Xb, Wqkb); Q=cols 0-1023, K=rest
    gemm8<1><<<dim3(8, 32, 1), blk8, 0, stream>>>(Xb, Wqkb, QKb, 16,
                                                  1024, 1024, 2048, 0, 0, 0, 1.f);
    // Vt projection: Vtb[1024,8192] = NT(Wvb, Xb)
    gemm8<1><<<dim3(32, 4, 1), blk8, 0, stream>>>(Wvb, Xb, Vtb, 16,
                                                  1024, 1024, 8192, 0, 0, 0, 1.f);
    // scores: S_b = NT(Q_b, K_b) / 32 -> f32 weights region
    gemm8<0><<<dim3(8, 8, 4), blk8, 0, stream>>>(QKb, QKb + 1024, wts, 16,
                                                 2048, 2048, 2048,
                                                 S * 2048, S * 2048, S * S,
                                                 0.03125f);
    // softmax rows (f32 in place) + bf16 copy
    softmax_rows<<<dim3(BT), blk, 0, stream>>>(wts, Wbf);

    // context: ctx_b = NT(Wbf_b, Vt[:, b*2048..]) ; K=2048 -> nkt=32
    gemm8<0><<<dim3(4, 8, 4), blk8, 0, stream>>>(Wbf, Vtb, ctx, 32,
                                                 2048, 8192, 1024,
                                                 S * S, S, S * D, 1.f);
}